// Round 14
// baseline (63.520 us; speedup 1.0000x reference)
//
#include <hip/hip_runtime.h>
#include <stdint.h>

// ---------------------------------------------------------------------------
// FastHelgasonLayer: weights are IFFTs of 16-sparse spectra => exactly rank-32.
//   W_fc = U_fc(2048x32)V_fc(32x8192), W_proj = U_pr(8192x32)V_pr(32x2048)
// Round 14: k_mid occupancy 4->8 waves/SIMD: 256-f chunks (37.5 KB LDS,
// 4 blocks/CU) + VGPR<=64 via __launch_bounds__(512,8) and a slim 16f/iter
// loop (4 accumulators, ILP 2). t2p grows to 32 slots. k_t1/k_out from r13.
// ---------------------------------------------------------------------------

typedef short bfrag8 __attribute__((ext_vector_type(8)));   // 8 bf16
typedef short bfrag4 __attribute__((ext_vector_type(4)));   // 4 bf16
typedef float f32x4  __attribute__((ext_vector_type(4)));

#define LMASK 8388607u      // 2^23 - 1
#define TWO_PI_OVER_L 7.4901405658478575e-7f

__device__ __forceinline__ unsigned short f2bf(float f) {
    unsigned u = __float_as_uint(f);
    u = (u + 0x7FFFu + ((u >> 16) & 1u)) >> 16;   // RTN-even
    return (unsigned short)u;
}
__device__ __forceinline__ float bf2f(unsigned short h) {
    unsigned u = ((unsigned)h) << 16;
    return __builtin_bit_cast(float, u);
}
__device__ __forceinline__ unsigned pk2bf(float a, float b) {
    unsigned ua = __float_as_uint(a) + 0x8000u;
    unsigned ub = __float_as_uint(b) + 0x8000u;
    return __builtin_amdgcn_perm(ub, ua, 0x07060302u);
}
__device__ __forceinline__ float gelu_fast(float x) {
    float xx = x * x;
    float t  = x * fmaf(xx, -0.1029437f, -2.3022083f);  // -2*sqrt(2/pi)*log2e*(1+c*xx)
    float e  = __builtin_amdgcn_exp2f(t);
    return x * __builtin_amdgcn_rcpf(1.0f + e);
}
__device__ __forceinline__ void sc_ph(unsigned ph, float& sn, float& cs) {
    __sincosf((float)ph * TWO_PI_OVER_L, &sn, &cs);
}
__device__ __forceinline__ void rot(float& c, float& s, float cd, float sd) {
    float cn = fmaf(c, cd, -s * sd);
    s = fmaf(s, cd, c * sd);
    c = cn;
}

#if defined(__has_builtin)
#if __has_builtin(__builtin_amdgcn_mfma_f32_16x16x16bf16_1k)
#define HAVE_MFMA16_1K 1
#endif
#endif
__device__ __forceinline__ void mfma16(f32x4& acc, bfrag4 a, bfrag4 b) {
#ifdef HAVE_MFMA16_1K
    acc = __builtin_amdgcn_mfma_f32_16x16x16bf16_1k(a, b, acc, 0, 0, 0);
#else
    asm("v_mfma_f32_16x16x16_bf16 %0, %1, %2, %0" : "+v"(acc) : "v"(a), "v"(b));
#endif
}

// dedup (last-write-wins): coeff kk survives only if no later j has same index
__device__ __forceinline__ bool keep_coef(const int* __restrict__ idx, int kk) {
    int v = idx[kk];
    bool keep = true;
    for (int j = kk + 1; j < 16; ++j) keep = keep && (idx[j] != v);
    return keep;
}

// ------------------ kernel 1: T1 = x @ U_fc  (512 blocks, r13) --------------
__global__ __launch_bounds__(512, 4) void k_t1(
    const float* __restrict__ x,                 // [8192 tok][2048]
    const float* __restrict__ fcr, const float* __restrict__ fci,
    const int* __restrict__ fidx,  const float* __restrict__ fcs,
    unsigned short* __restrict__ t1)             // [512 g][16 tok][32 r] bf16
{
    __shared__ float red[8 * 512];
    const int tid  = threadIdx.x;
    const int w    = tid >> 6;
    const int lane = tid & 63;
    const int lr   = lane & 15;
    const int hi   = lane >> 4;
    const size_t tok0 = (size_t)blockIdx.x * 16;

    const float sc = fcs[0] * (1.0f / 8388608.0f);
    const int p   = lr & 1;
    const int kk0 = lr >> 1, kk1 = 8 + (lr >> 1);
    unsigned s0, s1; float a0, b0, a1, b1;
    {
        bool k0 = keep_coef(fidx, kk0), k1 = keep_coef(fidx, kk1);
        s0 = (((unsigned)fidx[kk0]) << 12) & LMASK;
        s1 = (((unsigned)fidx[kk1]) << 12) & LMASK;
        a0 = k0 ? fcr[kk0] * sc : 0.f;  b0 = k0 ? fci[kk0] * sc : 0.f;
        a1 = k1 ? fcr[kk1] * sc : 0.f;  b1 = k1 ? fci[kk1] * sc : 0.f;
    }
    const float al0 = p ? b0 : a0, be0 = p ? a0 : -b0;
    const float al1 = p ? b1 : a1, be1 = p ? a1 : -b1;
    float c1r0, s1r0, c32r0, s32r0, cse0, sse0;   // step-1, step-32, seed
    float c1r1, s1r1, c32r1, s32r1, cse1, sse1;
    {
        const unsigned kb = (unsigned)(w * 256 + hi * 8);
        float sn, cs_;
        sc_ph(s0, sn, cs_);                    c1r0 = cs_;  s1r0 = sn;
        sc_ph((s0 * 32u) & LMASK, sn, cs_);    c32r0 = cs_; s32r0 = sn;
        sc_ph((s0 * kb) & LMASK, sn, cs_);     cse0 = cs_;  sse0 = sn;
        sc_ph(s1, sn, cs_);                    c1r1 = cs_;  s1r1 = sn;
        sc_ph((s1 * 32u) & LMASK, sn, cs_);    c32r1 = cs_; s32r1 = sn;
        sc_ph((s1 * kb) & LMASK, sn, cs_);     cse1 = cs_;  sse1 = sn;
    }

    f32x4 acc[2];
    { f32x4 z = {0.f,0.f,0.f,0.f}; acc[0] = z; acc[1] = z; }
    #pragma unroll 2
    for (int s = 0; s < 8; ++s) {
        int k = w * 256 + s * 32 + hi * 8;
        const float* xp = x + (tok0 + lr) * 2048 + k;
        float4 v0 = *(const float4*)xp;
        float4 v1 = *(const float4*)(xp + 4);
        uint4 aw = make_uint4(pk2bf(v0.x, v0.y), pk2bf(v0.z, v0.w),
                              pk2bf(v1.x, v1.y), pk2bf(v1.z, v1.w));
        bfrag8 af = __builtin_bit_cast(bfrag8, aw);
        float e0[8], e1[8];
        {
            float c = cse0, s_ = sse0;
            #pragma unroll
            for (int t = 0; t < 8; ++t) {
                e0[t] = fmaf(al0, c, be0 * s_);
                if (t < 7) rot(c, s_, c1r0, s1r0);
            }
            rot(cse0, sse0, c32r0, s32r0);
        }
        {
            float c = cse1, s_ = sse1;
            #pragma unroll
            for (int t = 0; t < 8; ++t) {
                e1[t] = fmaf(al1, c, be1 * s_);
                if (t < 7) rot(c, s_, c1r1, s1r1);
            }
            rot(cse1, sse1, c32r1, s32r1);
        }
        uint4 bw0 = make_uint4(pk2bf(e0[0], e0[1]), pk2bf(e0[2], e0[3]),
                               pk2bf(e0[4], e0[5]), pk2bf(e0[6], e0[7]));
        uint4 bw1 = make_uint4(pk2bf(e1[0], e1[1]), pk2bf(e1[2], e1[3]),
                               pk2bf(e1[4], e1[5]), pk2bf(e1[6], e1[7]));
        bfrag8 bf0 = __builtin_bit_cast(bfrag8, bw0);
        bfrag8 bf1 = __builtin_bit_cast(bfrag8, bw1);
        acc[0] = __builtin_amdgcn_mfma_f32_16x16x32_bf16(af, bf0, acc[0], 0, 0, 0);
        acc[1] = __builtin_amdgcn_mfma_f32_16x16x32_bf16(af, bf1, acc[1], 0, 0, 0);
    }
    #pragma unroll
    for (int nj = 0; nj < 2; ++nj)      // C: row=tok(4hi+r), col=r(nj*16+lr)
        #pragma unroll
        for (int r = 0; r < 4; ++r)
            red[w * 512 + (hi * 4 + r) * 32 + nj * 16 + lr] = acc[nj][r];
    __syncthreads();
    float s = 0.f;
    #pragma unroll
    for (int w2 = 0; w2 < 8; ++w2) s += red[w2 * 512 + tid];
    t1[(size_t)blockIdx.x * 512 + tid] = f2bf(s);
}

// -------- kernel 2: middle loop — 256-f chunks, 8 waves/SIMD ----------------
// grid (32 fc, 32 gy); block: 8 waves x 2 groups; LDS 37.5 KB; VGPR <= 64.
__global__ __launch_bounds__(512, 8) void k_mid(
    const unsigned short* __restrict__ t1,       // [512 g][512]
    const int* __restrict__ fidx,
    const int* __restrict__ pidx,
    const float* __restrict__ prr, const float* __restrict__ pri,
    const float* __restrict__ prs,
    const float* __restrict__ fcb,               // [8192]
    unsigned short* __restrict__ t2p)            // [32 fc][512 g][512] bf16
{
    __shared__ __align__(16) unsigned short vfc[256 * 40];   // 20 KB [f_l][40]
    __shared__ __align__(16) unsigned short upr[32 * 264];   // 16.5 KB [r2][264]
    __shared__ float lbias[256];                             // 1 KB
    const int tid  = threadIdx.x;
    const int w    = tid >> 6;
    const int lane = tid & 63;
    const int lr   = lane & 15;
    const int hi   = lane >> 4;
    const int fc   = blockIdx.x;            // f-chunk 0..31 (256 f each)

    if (tid < 256) {
        // ---- stage V_fc^T rows: thread t -> f_local t (16 sincos) ----------
        int jg = fc * 256 + tid;
        unsigned m = ((unsigned)jg) >> 1;
        int pj = jg & 1;
        unsigned short* row = vfc + tid * 40;
        #pragma unroll
        for (int k = 0; k < 16; ++k) {
            float sn, cs;
            sc_ph(((((unsigned)fidx[k]) & LMASK) * m) & LMASK, sn, cs);
            row[2 * k]     = f2bf(pj ? sn : cs);
            row[2 * k + 1] = f2bf(pj ? cs : -sn);
        }
        lbias[tid] = fcb[fc * 256 + tid];
    } else {
        // ---- stage U_pr^T rows: thread -> (k, 16 f) (16 sincos) ------------
        const float scp = prs[0] * (1.0f / 8388608.0f);
        int idx = tid - 256;
        int k  = idx >> 4;
        int f0 = (idx & 15) * 16;
        bool kp = keep_coef(pidx, k);
        unsigned s = (((unsigned)pidx[k]) << 10) & LMASK;
        float a = kp ? prr[k] * scp : 0.f;
        float b = kp ? pri[k] * scp : 0.f;
        unsigned short* r0 = upr + (2 * k) * 264 + f0;
        unsigned short* r1 = upr + (2 * k + 1) * 264 + f0;
        unsigned fg = (unsigned)(fc * 256 + f0);
        #pragma unroll
        for (int t = 0; t < 16; ++t) {
            float sn, cs;
            sc_ph((s * (fg + t)) & LMASK, sn, cs);
            r0[t] = f2bf(fmaf(a, cs, -b * sn));
            r1[t] = f2bf(fmaf(a, sn, b * cs));
        }
    }
    __syncthreads();

    // ---- per-wave: 2 token-groups, 16 iters x 16 f, no barriers ------------
    const int ga = blockIdx.y * 16 + w * 2, gb = ga + 1;
    const int toff = lr * 32 + hi * 8;
    const bfrag8 tA = *(const bfrag8*)(t1 + (size_t)ga * 512 + toff);
    const bfrag8 tB = *(const bfrag8*)(t1 + (size_t)gb * 512 + toff);
    f32x4 aA0 = {0.f,0.f,0.f,0.f}, aA1 = {0.f,0.f,0.f,0.f};
    f32x4 aB0 = {0.f,0.f,0.f,0.f}, aB1 = {0.f,0.f,0.f,0.f};

    #pragma unroll 1
    for (int it = 0; it < 16; ++it) {
        const int f0 = it * 16;
        bfrag8 va = *(const bfrag8*)(vfc + (f0 + lr) * 40 + hi * 8);
        f32x4 cb = *(const f32x4*)(lbias + f0 + hi * 4);
        bfrag4 u0 = *(const bfrag4*)(upr + lr * 264 + f0 + hi * 4);
        bfrag4 u1 = *(const bfrag4*)(upr + (16 + lr) * 264 + f0 + hi * 4);
        // S tiles (16f x 16tok), bias via C-operand; 2 independent chains
        f32x4 sA = __builtin_amdgcn_mfma_f32_16x16x32_bf16(va, tA, cb, 0, 0, 0);
        f32x4 sB = __builtin_amdgcn_mfma_f32_16x16x32_bf16(va, tB, cb, 0, 0, 0);
        // gelu + pack (C-layout == K=16 B-frag)
        uint2 hwA = make_uint2(pk2bf(gelu_fast(sA[0]), gelu_fast(sA[1])),
                               pk2bf(gelu_fast(sA[2]), gelu_fast(sA[3])));
        uint2 hwB = make_uint2(pk2bf(gelu_fast(sB[0]), gelu_fast(sB[1])),
                               pk2bf(gelu_fast(sB[2]), gelu_fast(sB[3])));
        bfrag4 hA = __builtin_bit_cast(bfrag4, hwA);
        bfrag4 hB = __builtin_bit_cast(bfrag4, hwB);
        // T2^T += U_pr^T * hT  (f-sum in accumulator)
        mfma16(aA0, u0, hA);
        mfma16(aA1, u1, hA);
        mfma16(aB0, u0, hB);
        mfma16(aB1, u1, hB);
    }

    // ---- direct t2p writes (lane holds r2 = 4hi+r [+16], tok = lr) ---------
    {
        unsigned short* oa = t2p + ((size_t)fc * 512 + ga) * 512;
        unsigned short* ob = t2p + ((size_t)fc * 512 + gb) * 512;
        *(uint2*)(oa + lr * 32 + hi * 4)      = make_uint2(pk2bf(aA0[0], aA0[1]), pk2bf(aA0[2], aA0[3]));
        *(uint2*)(oa + lr * 32 + 16 + hi * 4) = make_uint2(pk2bf(aA1[0], aA1[1]), pk2bf(aA1[2], aA1[3]));
        *(uint2*)(ob + lr * 32 + hi * 4)      = make_uint2(pk2bf(aB0[0], aB0[1]), pk2bf(aB0[2], aB0[3]));
        *(uint2*)(ob + lr * 32 + 16 + hi * 4) = make_uint2(pk2bf(aB1[0], aB1[1]), pk2bf(aB1[2], aB1[3]));
    }
}

// ------ kernel 3: out = (sum_fc T2p) @ V_pr^T + b2  (rotation chains) -------
__global__ __launch_bounds__(512, 4) void k_out(
    const unsigned short* __restrict__ t2p,      // [32][512 g][512] bf16
    const int* __restrict__ pidx,
    const float* __restrict__ prb,               // [2048]
    float* __restrict__ out)                     // [8192 tok][2048]
{
    __shared__ unsigned short lT[512];
    const int tid  = threadIdx.x;
    const int w    = tid >> 6;
    const int lane = tid & 63;
    const int lr   = lane & 15;
    const int hi   = lane >> 4;
    const int g    = blockIdx.x;
    const size_t tok0 = (size_t)g * 16;

    {
        float s = 0.f;
        #pragma unroll
        for (int c = 0; c < 32; ++c)
            s += bf2f(t2p[((size_t)c * 512 + g) * 512 + tid]);
        lT[tid] = f2bf(s);
    }
    const int pd = lr & 1;
    float rc0, rs0, rc1, rs1, rc2, rs2, rc3, rs3;
    float dc0, ds0, dc1, ds1, dc2, ds2, dc3, ds3;
    {
        unsigned m0 = (unsigned)(w * 128 + (lr >> 1));
        float sn, cs_;
        unsigned k0 = ((unsigned)pidx[hi * 4 + 0]) & LMASK;
        unsigned k1 = ((unsigned)pidx[hi * 4 + 1]) & LMASK;
        unsigned k2 = ((unsigned)pidx[hi * 4 + 2]) & LMASK;
        unsigned k3 = ((unsigned)pidx[hi * 4 + 3]) & LMASK;
        sc_ph((k0 * m0) & LMASK, sn, cs_); rc0 = cs_; rs0 = sn;
        sc_ph((k0 * 8u) & LMASK, sn, cs_); dc0 = cs_; ds0 = sn;
        sc_ph((k1 * m0) & LMASK, sn, cs_); rc1 = cs_; rs1 = sn;
        sc_ph((k1 * 8u) & LMASK, sn, cs_); dc1 = cs_; ds1 = sn;
        sc_ph((k2 * m0) & LMASK, sn, cs_); rc2 = cs_; rs2 = sn;
        sc_ph((k2 * 8u) & LMASK, sn, cs_); dc2 = cs_; ds2 = sn;
        sc_ph((k3 * m0) & LMASK, sn, cs_); rc3 = cs_; rs3 = sn;
        sc_ph((k3 * 8u) & LMASK, sn, cs_); dc3 = cs_; ds3 = sn;
    }
    __syncthreads();
    const bfrag8 t2a = *(const bfrag8*)(lT + lr * 32 + hi * 8);
    #pragma unroll 4
    for (int nj = 0; nj < 16; ++nj) {
        int d = w * 256 + nj * 16 + lr;
        float v0 = pd ? rs0 : rc0, v1 = pd ? rc0 : -rs0;
        float v2 = pd ? rs1 : rc1, v3 = pd ? rc1 : -rs1;
        float v4 = pd ? rs2 : rc2, v5 = pd ? rc2 : -rs2;
        float v6 = pd ? rs3 : rc3, v7 = pd ? rc3 : -rs3;
        uint4 pw = make_uint4(pk2bf(v0, v1), pk2bf(v2, v3),
                              pk2bf(v4, v5), pk2bf(v6, v7));
        bfrag8 vp = __builtin_bit_cast(bfrag8, pw);
        float bn = prb[d];
        f32x4 c4 = {bn, bn, bn, bn};
        f32x4 o = __builtin_amdgcn_mfma_f32_16x16x32_bf16(t2a, vp, c4, 0, 0, 0);
        #pragma unroll
        for (int r = 0; r < 4; ++r)
            out[(tok0 + hi * 4 + r) * 2048 + d] = o[r];
        rot(rc0, rs0, dc0, ds0);
        rot(rc1, rs1, dc1, ds1);
        rot(rc2, rs2, dc2, ds2);
        rot(rc3, rs3, dc3, ds3);
    }
}

// ---------------------------------------------------------------------------
extern "C" void kernel_launch(void* const* d_in, const int* in_sizes, int n_in,
                              void* d_out, int out_size, void* d_ws, size_t ws_size,
                              hipStream_t stream) {
    (void)in_sizes; (void)n_in; (void)out_size; (void)ws_size;
    const float* x   = (const float*)d_in[0];
    const float* fcr = (const float*)d_in[1];
    const float* fci = (const float*)d_in[2];
    const float* fcs = (const float*)d_in[3];
    const float* prr = (const float*)d_in[4];
    const float* pri = (const float*)d_in[5];
    const float* prs = (const float*)d_in[6];
    const float* fcb = (const float*)d_in[7];
    const float* prb = (const float*)d_in[8];
    const int* fidx  = (const int*)d_in[9];
    const int* pidx  = (const int*)d_in[10];
    float* out = (float*)d_out;
    char* ws = (char*)d_ws;

    size_t off = 0;
    auto take = [&](size_t bytes) { size_t p = off; off = (off + bytes + 255) & ~(size_t)255; return p; };
    unsigned short* t1  = (unsigned short*)(ws + take((size_t)8192 * 32 * 2));        // T1 [8192][32] bf16
    unsigned short* t2p = (unsigned short*)(ws + take((size_t)32 * 512 * 512 * 2));   // T2 partials [32][512][512] bf16

    k_t1 <<<dim3(512),    512, 0, stream>>>(x, fcr, fci, fidx, fcs, t1);
    k_mid<<<dim3(32, 32), 512, 0, stream>>>(t1, fidx, pidx, prr, pri, prs, fcb, t2p);
    k_out<<<dim3(512),    512, 0, stream>>>(t2p, pidx, prb, out);
}